// Round 1
// baseline (431.464 us; speedup 1.0000x reference)
//
#include <hip/hip_runtime.h>
#include <math.h>

// Problem constants (FlaxHouseholderRoPE): B=2, S=4096, H=32, D=128, R=2
#define BB 2
#define SS 4096
#define HH 32
#define DD 128
#define EPS_C 1e-6f
// -log2(10000)/64  (inv_freq[p] = 10000^(-p/64) = exp2(p * C_LOG))
#define C_LOG (-0.20762050593046015f)

// Native 16B vector type — required by __builtin_nontemporal_load/store
typedef float vf4 __attribute__((ext_vector_type(4)));

// Sum across each 32-lane half of the wave using single-instruction ds_swizzle
// (BitMode: offset = (xor<<10)|(or<<5)|and; and=0x1F confines to 32-lane groups).
__device__ __forceinline__ float hsum32(float v) {
    v += __int_as_float(__builtin_amdgcn_ds_swizzle(__float_as_int(v), 0x041F)); // xor 1
    v += __int_as_float(__builtin_amdgcn_ds_swizzle(__float_as_int(v), 0x081F)); // xor 2
    v += __int_as_float(__builtin_amdgcn_ds_swizzle(__float_as_int(v), 0x101F)); // xor 4
    v += __int_as_float(__builtin_amdgcn_ds_swizzle(__float_as_int(v), 0x201F)); // xor 8
    v += __int_as_float(__builtin_amdgcn_ds_swizzle(__float_as_int(v), 0x401F)); // xor 16
    return v;
}

__device__ __forceinline__ float dot4(vf4 a, vf4 b) {
    return a.x * b.x + a.y * b.y + a.z * b.z + a.w * b.w;
}

// Rank-2 composed Householder + RoPE epilogue for one vf4 fragment.
// c0 = rs0*d0 ; c1 = rs1*(d1 - c0*t01)  (equivalent to sequential reflections)
__device__ __forceinline__ vf4 finish(vf4 x, vf4 v0, vf4 v1,
                                      float d0, float d1,
                                      float rs0, float rs1, float t01,
                                      float sa, float ca, float sb, float cb) {
    const float c0 = d0 * rs0;
    const float c1 = (d1 - c0 * t01) * rs1;
    x.x -= c0 * v0.x + c1 * v1.x;
    x.y -= c0 * v0.y + c1 * v1.y;
    x.z -= c0 * v0.z + c1 * v1.z;
    x.w -= c0 * v0.w + c1 * v1.w;
    vf4 r;
    r.x = x.x * ca - x.y * sa;  r.y = x.x * sa + x.y * ca;
    r.z = x.z * cb - x.w * sb;  r.w = x.z * sb + x.w * cb;
    return r;
}

// Per-iteration float offset: iteration it (0..15) covers bs = bs0 + (it>>1)*1024 + (it&1)
__device__ __forceinline__ size_t it_off(int it) {
    return (size_t)(it >> 1) * ((size_t)1024 * HH * DD)
         + (size_t)(it & 1)  * ((size_t)HH * DD);
}

__global__ __launch_bounds__(256, 6)
void hh_rope_kernel(const float* __restrict__ q, const float* __restrict__ k,
                    const float* __restrict__ pos, const float* __restrict__ refl,
                    float* __restrict__ oq, float* __restrict__ ok)
{
    const int lane   = threadIdx.x & 63;
    const int wid    = (blockIdx.x << 2) + (threadIdx.x >> 6);
    const int hp     = wid & 15;        // wave covers heads h = 2*hp, 2*hp+1
    const int slice  = wid >> 4;        // 512 slices over bs
    const int half   = lane >> 5;
    const int j      = lane & 31;       // vf4 index within the 128-float row
    const int h      = (hp << 1) + half;

    // Hoisted per-wave: reflector fragments, 2/(|v|^2+eps), cross term v1.v0
    const vf4 v0 = ((const vf4*)(refl + (size_t)(h * 2 + 0) * DD))[j];
    const vf4 v1 = ((const vf4*)(refl + (size_t)(h * 2 + 1) * DD))[j];
    const float rs0 = 2.0f / (hsum32(dot4(v0, v0)) + EPS_C);
    const float rs1 = 2.0f / (hsum32(dot4(v1, v1)) + EPS_C);
    const float t01 = hsum32(dot4(v1, v0));

    // Lane j holds RoPE pairs 2j and 2j+1
    const float if0 = exp2f((float)(2 * j)     * C_LOG);
    const float if1 = exp2f((float)(2 * j + 1) * C_LOG);

    const int bs0 = slice << 1;
    const size_t base = ((size_t)bs0 * HH + h) * DD + 4 * (size_t)j;
    const float* qp = q  + base;
    const float* kp = k  + base;
    float*      oqp = oq + base;
    float*      okp = ok + base;

    // 3-stage software pipeline: 2 rows prefetched ahead of the row being
    // computed, so >=2 nontemporal loads are in flight across the entire
    // dot -> 5x ds_swizzle -> finish -> store chain (~2 bodies > HBM latency).
    vf4 aq = __builtin_nontemporal_load((const vf4*)(qp + it_off(0)));
    vf4 ak = __builtin_nontemporal_load((const vf4*)(kp + it_off(0)));
    vf4 bq = __builtin_nontemporal_load((const vf4*)(qp + it_off(1)));
    vf4 bk = __builtin_nontemporal_load((const vf4*)(kp + it_off(1)));

#pragma unroll
    for (int it = 0; it < 16; ++it) {
        // Issue the it+2 loads FIRST — before any dependent work on row `it`.
        vf4 cq, ck;
        if (it < 14) {
            const size_t poff = it_off(it + 2);
            cq = __builtin_nontemporal_load((const vf4*)(qp + poff));
            ck = __builtin_nontemporal_load((const vf4*)(kp + poff));
        }

        const int bs = bs0 + ((it >> 1) << 10) + (it & 1);
        const float p = pos[bs & (SS - 1)];   // uniform per wave -> scalar load
        float sa, ca, sb, cb;
        __sincosf(p * if0, &sa, &ca);
        __sincosf(p * if1, &sb, &cb);

        // 4 independent reductions -> ds_swizzle chains pipeline
        const float dq0 = hsum32(dot4(aq, v0));
        const float dq1 = hsum32(dot4(aq, v1));
        const float dk0 = hsum32(dot4(ak, v0));
        const float dk1 = hsum32(dot4(ak, v1));

        const size_t off = it_off(it);
        vf4 r;
        r = finish(aq, v0, v1, dq0, dq1, rs0, rs1, t01, sa, ca, sb, cb);
        __builtin_nontemporal_store(r, (vf4*)(oqp + off));
        r = finish(ak, v0, v1, dk0, dk1, rs0, rs1, t01, sa, ca, sb, cb);
        __builtin_nontemporal_store(r, (vf4*)(okp + off));

        // rotate pipeline registers (renames after full unroll — free)
        aq = bq; ak = bk;
        if (it < 14) { bq = cq; bk = ck; }
    }
}

extern "C" void kernel_launch(void* const* d_in, const int* in_sizes, int n_in,
                              void* d_out, int out_size, void* d_ws, size_t ws_size,
                              hipStream_t stream) {
    const float* q    = (const float*)d_in[0];
    const float* k    = (const float*)d_in[1];
    const float* pos  = (const float*)d_in[2];
    const float* refl = (const float*)d_in[3];

    float* oq = (float*)d_out;
    float* ok = oq + (size_t)BB * SS * HH * DD;   // outputs concatenated (q_rope, k_rope)

    // 2048 blocks x 256 threads = 8192 waves = 16 h-pairs x 512 slices
    hh_rope_kernel<<<dim3(2048), dim3(256), 0, stream>>>(q, k, pos, refl, oq, ok);
}